// Round 6
// baseline (686.330 us; speedup 1.0000x reference)
//
#include <hip/hip_runtime.h>
#include <hip/hip_bf16.h>
#include <math.h>

#define H 128
#define RS 136    // LDS row stride in shorts (128 + 8 pad; keeps ds_read_b128 16B-aligned)
#define BSH 9     // bin shift: 512 nodes per bin
#define BINW 512
#define BCAP 11264  // max edges/bin for LDS sort
#define BSLOT 12288 // per-bin slot capacity in temp (direct scatter)
#define KEDGE 4096  // edges per partition block
#define EPT 16      // edges per thread (KEDGE/256)
#define MAXBINS 1024

typedef __attribute__((ext_vector_type(8))) short short8;
typedef __attribute__((ext_vector_type(4))) short short4v;
typedef __attribute__((ext_vector_type(2))) short short2v;
typedef __attribute__((ext_vector_type(4))) float f32x4;
typedef __attribute__((ext_vector_type(2))) _Float16 half2v;
typedef __attribute__((ext_vector_type(4))) _Float16 half4v;
typedef __attribute__((ext_vector_type(8))) _Float16 half8v;

// fp32 -> bf16 (RNE); values here are finite (no NaN handling needed)
__device__ __forceinline__ short f2bf(float f) {
    unsigned u = __float_as_uint(f);
    u += 0x7fff + ((u >> 16) & 1);
    return (short)(u >> 16);
}
__device__ __forceinline__ float bf2f(short h) {
    return __uint_as_float(((unsigned)(unsigned short)h) << 16);
}

// ---------------- CSR build (direct slot scatter -> scan -> in-bin sort+rowptr) ----------
// Node space concatenated: [NP(isa) | NG(rel) | NP(rev)].

// stage 1: block-aggregated partition straight into per-bin slot regions.
// Per block: LDS histogram over bins, ONE global atomicAdd per touched bin (reserve a
// contiguous run in that bin's slot region), then scatter from registers via LDS cursors.
// bin_cur doubles as the per-bin count (starts at 0).
// payload: src | (local_dst << 16)
__global__ __launch_bounds__(256) void bin_scatter_kernel(
    const int* __restrict__ e0, int E0, const int* __restrict__ e1, int E1,
    const int* __restrict__ e2, int E2, int* __restrict__ bin_cur,
    int* __restrict__ temp, int NPn, int NGn, int nbins, int E_tot) {
    __shared__ int hist[MAXBINS];
    __shared__ int cur[MAXBINS];
    int t = threadIdx.x;
    for (int i = t; i < nbins; i += 256) hist[i] = 0;
    __syncthreads();
    int vals[EPT], bins[EPT];
    int base_e = blockIdx.x * KEDGE;
#pragma unroll
    for (int j = 0; j < EPT; ++j) {
        int g = base_e + j * 256 + t;      // coalesced within each j-step
        int b = -1, v = 0;
        if (g < E_tot) {
            const int* ed; int E, lo, nbase;
            if (g < E0) { ed = e0; E = E0; lo = g; nbase = 0; }
            else if (g < E0 + E1) { ed = e1; E = E1; lo = g - E0; nbase = NPn; }
            else { ed = e2; E = E2; lo = g - E0 - E1; nbase = NPn + NGn; }
            int src = ed[lo];
            int gdst = nbase + ed[E + lo];
            v = src | ((gdst & (BINW - 1)) << 16);
            b = gdst >> BSH;
            atomicAdd(&hist[b], 1);        // LDS atomic
        }
        vals[j] = v;
        bins[j] = b;
    }
    __syncthreads();
    for (int i = t; i < nbins; i += 256) {
        int h = hist[i];
        cur[i] = h ? atomicAdd(&bin_cur[i * 16], h) : 0;   // reserve run (local slot base)
    }
    __syncthreads();
#pragma unroll
    for (int j = 0; j < EPT; ++j) {
        if (bins[j] >= 0) {
            int p = atomicAdd(&cur[bins[j]], 1);           // LDS atomic -> local slot
            if (p < BSLOT) temp[(size_t)bins[j] * BSLOT + p] = vals[j];
        }
    }
}

// stage 2: exclusive scan of bin counts -> bin_base[0..nbins].
__global__ __launch_bounds__(1024) void scan_bins(const int* __restrict__ bin_cur, int nbins,
                                                  int* __restrict__ bin_base) {
    __shared__ int sh[1024];
    int t = threadIdx.x;
    int v = 0;
    if (t < nbins) { v = bin_cur[t * 16]; if (v > BSLOT) v = BSLOT; }
    sh[t] = v;
    __syncthreads();
    for (int off = 1; off < 1024; off <<= 1) {
        int u = (t >= off) ? sh[t - off] : 0;
        __syncthreads();
        sh[t] += u;
        __syncthreads();
    }
    if (t < nbins) bin_base[t] = sh[t] - v;    // exclusive
    if (t == nbins - 1) bin_base[nbins] = sh[t];
}

// stage 3: per-bin LDS counting sort. Builds per-node histogram + scan in LDS
// (producing rowptr for this bin), then places edges; col written fully coalesced.
__global__ __launch_bounds__(256) void bin_sort_kernel(
    const int* __restrict__ bin_base, const int* __restrict__ temp,
    int* __restrict__ col, int* __restrict__ rowptr, int n_tot, int nbins) {
    __shared__ int srt[BCAP];
    __shared__ int cur[BINW];
    __shared__ int pfx[BINW];
    __shared__ int red[256];
    int b = blockIdx.x;
    int start = b << BSH;
    int nodes = n_tot - start; if (nodes > BINW) nodes = BINW;
    int t = threadIdx.x;
    int base = bin_base[b];
    int count = bin_base[b + 1] - base;
    const int* __restrict__ tb = temp + (size_t)b * BSLOT;
    // per-node histogram of this bin's payloads
    for (int i = t; i < BINW; i += 256) cur[i] = 0;
    __syncthreads();
    for (int i = t; i < count; i += 256)
        atomicAdd(&cur[(tb[i] >> 16) & (BINW - 1)], 1);
    __syncthreads();
    // exclusive scan of 512 counts (2 per thread + 256-wide Hillis-Steele)
    int a0 = cur[2 * t], a1 = cur[2 * t + 1];
    red[t] = a0 + a1;
    __syncthreads();
    for (int off = 1; off < 256; off <<= 1) {
        int u = (t >= off) ? red[t - off] : 0;
        __syncthreads();
        red[t] += u;
        __syncthreads();
    }
    int excl = red[t] - (a0 + a1);
    pfx[2 * t] = excl;
    pfx[2 * t + 1] = excl + a0;
    __syncthreads();
    // rowptr for this bin (boundary start+BINW written by the next bin; last bin: n_tot)
    for (int i = t; i < nodes; i += 256) rowptr[start + i] = base + pfx[i];
    if (b == nbins - 1 && t == 0) rowptr[n_tot] = base + count;
    // reset cursors to local starts
    for (int i = t; i < BINW; i += 256) cur[i] = pfx[i];
    __syncthreads();
    if (count <= BCAP) {
        for (int i = t; i < count; i += 256) {
            int v = tb[i];
            int p = atomicAdd(&cur[(v >> 16) & (BINW - 1)], 1);
            srt[p] = v & 0xFFFF;
        }
        __syncthreads();
        for (int i = t; i < count; i += 256) col[base + i] = srt[i];
    } else {  // fallback (not expected): direct global scatter
        for (int i = t; i < count; i += 256) {
            int v = tb[i];
            int p = atomicAdd(&cur[(v >> 16) & (BINW - 1)], 1);
            col[base + p] = v & 0xFFFF;
        }
    }
}

// ---------------- W pack: fp32 [k][n] -> MFMA B-fragment order, split bf16 hi/lo ----------------
// 15 matrices (5 per layer: Wl_isa, Wl_rev, Wsum=Wr_isa+Wr_rev, Wl_rel, Wr_rel).
// B-operand layout: n = ct*16 + (lane&15), k = kc*32 + (lane>>4)*8 + j.

struct WSrc { const float* a[15]; const float* b[15]; };

__global__ __launch_bounds__(256) void pack_w_kernel(WSrc src, short* __restrict__ whi,
                                                     short* __restrict__ wlo) {
    int idx = blockIdx.x * 256 + threadIdx.x;   // (mat, kc, ct, lane)
    if (idx >= 15 * 4 * 8 * 64) return;
    int lane = idx & 63;
    int ct = (idx >> 6) & 7;
    int kc = (idx >> 9) & 3;
    int mat = idx >> 11;
    const float* A = src.a[mat];
    const float* Bp = src.b[mat];
    int n = ct * 16 + (lane & 15);
    int kbase = kc * 32 + (lane >> 4) * 8;
    size_t o = (size_t)idx * 8;
    for (int j = 0; j < 8; ++j) {
        float v = A[(size_t)(kbase + j) * H + n];
        if (Bp) v += Bp[(size_t)(kbase + j) * H + n];
        short h = f2bf(v);
        whi[o + j] = h;
        wlo[o + j] = f2bf(v - bf2f(h));
    }
}

// ---------------- fp32 -> fp16 mirror convert (layer-0 inputs, both matrices) ----------------

__global__ __launch_bounds__(256) void cvt16_kernel(const float* __restrict__ xa, int n4a,
                                                    const float* __restrict__ xb, int n4b,
                                                    _Float16* __restrict__ ya,
                                                    _Float16* __restrict__ yb) {
    int i = blockIdx.x * 256 + threadIdx.x;
    const float* x; _Float16* y;
    if (i < n4a) { x = xa + (size_t)i * 4; y = ya + (size_t)i * 4; }
    else if (i < n4a + n4b) { x = xb + (size_t)(i - n4a) * 4; y = yb + (size_t)(i - n4a) * 4; }
    else return;
    f32x4 v = *(const f32x4*)x;
    half4v h;
#pragma unroll
    for (int k = 0; k < 4; ++k) h[k] = (_Float16)v[k];
    *(half4v*)y = h;
}

// ---------------- 4-row interleaved scalar-base fp16 segment mean ----------------
// Wave computes 4 dst-row means in lockstep 8-edge chunks: 32 independent gathers in
// flight per iteration (4x the old per-row MLP -> hides the L2/HBM round-trip that made
// the fused gather latency-bound). Lane covers 2 features (voff = lane*2); row bases go
// through readfirstlane -> global_load saddr+voffset. Ragged tails: per-row wave-uniform
// active branch + clamped duplicate index (L1 hit) with weight 0. Empty rows: cnt=0 ->
// never active, safe index 0, mean 0.

__device__ __forceinline__ void seg8x4(const _Float16* __restrict__ x,
                                       const int* __restrict__ rowptr,
                                       const int* __restrict__ col,
                                       const int rb[4], int voff, float2 out[4]) {
    int beg[4], cnt[4], last[4];
    int mc = 0;
#pragma unroll
    for (int r = 0; r < 4; ++r) {
        int b = rowptr[rb[r]];
        int e = rowptr[rb[r] + 1];
        int c = e - b;
        beg[r] = b;
        cnt[r] = c;
        last[r] = (c > 0) ? e - 1 : 0;
        int ch = (c + 7) >> 3;
        if (ch > mc) mc = ch;
    }
    float ax[4] = {0.f, 0.f, 0.f, 0.f};
    float ay[4] = {0.f, 0.f, 0.f, 0.f};
    for (int c = 0; c < mc; ++c) {
        half2v v[4][8];
#pragma unroll
        for (int r = 0; r < 4; ++r) {
            if (c * 8 < cnt[r]) {            // wave-uniform (scalar rowptr data)
#pragma unroll
                for (int i = 0; i < 8; ++i) {
                    int p = beg[r] + c * 8 + i;
                    if (p > last[r]) p = last[r];                  // dup -> L1 hit
                    int si = __builtin_amdgcn_readfirstlane(col[p]);
                    v[r][i] = *(const half2v*)(x + (size_t)si * H + voff);
                }
            }
        }
#pragma unroll
        for (int r = 0; r < 4; ++r) {
            if (c * 8 < cnt[r]) {
                int rem = cnt[r] - c * 8;    // > 0
#pragma unroll
                for (int i = 0; i < 8; ++i) {
                    float m = (i < rem) ? 1.0f : 0.0f;
                    ax[r] = fmaf((float)v[r][i][0], m, ax[r]);
                    ay[r] = fmaf((float)v[r][i][1], m, ay[r]);
                }
            }
        }
    }
#pragma unroll
    for (int r = 0; r < 4; ++r) {
        int c = cnt[r]; if (c < 1) c = 1;
        float inv = 1.0f / (float)c;
        out[r] = (float2){ax[r] * inv, ay[r] * inv};
    }
}

// ---------------- fused SAGE layer: gather-mean -> LDS A-tile -> split-bf16 MFMA ----------------
// Each 64-row block builds its A-tile per term: gather terms compute per-row means
// directly into LDS (wave w owns rows 16w..16w+15, processed as 4 interleaved groups of
// 4; hi/lo split in-register), copy terms stream pre-split planes (or fp32 layer-0
// inputs). Epilogue: fp16 mirror + split-bf16 planes (in-place on own rows only).

struct GTerm {
    const _Float16* x;   // gather source mirror (kind: gather if non-null)
    int rbase;           // rowptr base index for this edge type
    const short* hi;     // pre-split planes (kind: copy if non-null)
    const short* lo;
    const float* f;      // fp32 source (layer 0 copy)
};

template <int NIN>
__global__ __launch_bounds__(256, 3) void fused_gnn(
    GTerm t0, GTerm t1, GTerm t2,
    const int* __restrict__ rowptr, const int* __restrict__ col,
    const short* __restrict__ whi, const short* __restrict__ wlo,
    int mat0, int mat1, int mat2,
    const float* __restrict__ b0, const float* __restrict__ b1,
    _Float16* __restrict__ out16, short* __restrict__ ohi, short* __restrict__ olo,
    int n_rows, int relu) {
    __shared__ short Ahi[64 * RS];
    __shared__ short Alo[64 * RS];
    const int tid = threadIdx.x;
    const int lane = tid & 63;
    const int wave = __builtin_amdgcn_readfirstlane(tid >> 6);
    const int r0 = blockIdx.x * 64;
    const int ct0 = wave * 2;
    const int m16 = lane & 15;
    const int acol = (lane >> 4) * 8;

    f32x4 acc[4][2];
#pragma unroll
    for (int mt = 0; mt < 4; ++mt)
#pragma unroll
        for (int c = 0; c < 2; ++c) acc[mt][c] = (f32x4){0.f, 0.f, 0.f, 0.f};

    const GTerm terms[3] = {t0, t1, t2};
    const int marr[3] = {mat0, mat1, mat2};

#pragma unroll
    for (int m = 0; m < NIN; ++m) {
        const GTerm& T = terms[m];
        __syncthreads();
        if (T.x) {                          // gather-mean term: wave w owns rows 16w..16w+15
            int voff = lane * 2;
#pragma unroll
            for (int g = 0; g < 4; ++g) {
                int rb[4];
#pragma unroll
                for (int r = 0; r < 4; ++r) {
                    int gr = r0 + wave * 16 + g * 4 + r;
                    if (gr >= n_rows) gr = n_rows - 1;   // dup row: harmless recompute
                    rb[r] = T.rbase + gr;
                }
                float2 s[4];
                seg8x4(T.x, rowptr, col, rb, voff, s);
#pragma unroll
                for (int r = 0; r < 4; ++r) {
                    int lrow = wave * 16 + g * 4 + r;
                    short h0 = f2bf(s[r].x), h1 = f2bf(s[r].y);
                    *(short2v*)&Ahi[lrow * RS + voff] = (short2v){h0, h1};
                    *(short2v*)&Alo[lrow * RS + voff] =
                        (short2v){f2bf(s[r].x - bf2f(h0)), f2bf(s[r].y - bf2f(h1))};
                }
            }
        } else if (T.hi) {                  // pre-split planes: pure copy
#pragma unroll
            for (int i = 0; i < 8; ++i) {
                int f = tid + i * 256;
                int row = f >> 5;
                int c4 = (f & 31) * 4;
                int gr = r0 + row;
                if (gr >= n_rows) gr = n_rows - 1;
                size_t o = (size_t)gr * H + c4;
                *(short4v*)&Ahi[row * RS + c4] = *(const short4v*)&T.hi[o];
                *(short4v*)&Alo[row * RS + c4] = *(const short4v*)&T.lo[o];
            }
        } else {                            // fp32 (layer 0): split on stage
            const float* __restrict__ A = T.f;
#pragma unroll
            for (int i = 0; i < 8; ++i) {
                int f = tid + i * 256;
                int row = f >> 5;
                int c4 = (f & 31) * 4;
                int gr = r0 + row;
                if (gr >= n_rows) gr = n_rows - 1;
                float4 v = *(const float4*)&A[(size_t)gr * H + c4];
                short h0 = f2bf(v.x), h1 = f2bf(v.y), h2 = f2bf(v.z), h3 = f2bf(v.w);
                *(short4v*)&Ahi[row * RS + c4] = (short4v){h0, h1, h2, h3};
                *(short4v*)&Alo[row * RS + c4] =
                    (short4v){f2bf(v.x - bf2f(h0)), f2bf(v.y - bf2f(h1)),
                              f2bf(v.z - bf2f(h2)), f2bf(v.w - bf2f(h3))};
            }
        }
        __syncthreads();
        const short* __restrict__ wh = whi + (size_t)marr[m] * (H * H);
        const short* __restrict__ wl = wlo + (size_t)marr[m] * (H * H);
        short8 bh[2][2], bl[2][2];
        {
            size_t f0 = ((size_t)ct0 * 64 + lane) * 8;
            bh[0][0] = *(const short8*)&wh[f0];
            bh[0][1] = *(const short8*)&wh[f0 + 512];
            bl[0][0] = *(const short8*)&wl[f0];
            bl[0][1] = *(const short8*)&wl[f0 + 512];
        }
#pragma unroll
        for (int kc = 0; kc < 4; ++kc) {
            if (kc < 3) {
                int nb = (kc + 1) & 1;
                size_t f = ((size_t)((kc + 1) * 8 + ct0) * 64 + lane) * 8;
                bh[nb][0] = *(const short8*)&wh[f];
                bh[nb][1] = *(const short8*)&wh[f + 512];
                bl[nb][0] = *(const short8*)&wl[f];
                bl[nb][1] = *(const short8*)&wl[f + 512];
            }
            int cb = kc & 1;
#pragma unroll
            for (int mt = 0; mt < 4; ++mt) {
                short8 ah = *(const short8*)&Ahi[(mt * 16 + m16) * RS + kc * 32 + acol];
                short8 al = *(const short8*)&Alo[(mt * 16 + m16) * RS + kc * 32 + acol];
#pragma unroll
                for (int c = 0; c < 2; ++c) {
                    acc[mt][c] = __builtin_amdgcn_mfma_f32_16x16x32_bf16(ah, bh[cb][c], acc[mt][c], 0, 0, 0);
                    acc[mt][c] = __builtin_amdgcn_mfma_f32_16x16x32_bf16(al, bh[cb][c], acc[mt][c], 0, 0, 0);
                    acc[mt][c] = __builtin_amdgcn_mfma_f32_16x16x32_bf16(ah, bl[cb][c], acc[mt][c], 0, 0, 0);
                }
            }
        }
    }

    const int rquad = (lane >> 4) * 4;
    const int ncol = lane & 15;
#pragma unroll
    for (int c = 0; c < 2; ++c) {
        int n = (ct0 + c) * 16 + ncol;
        float bs = b0[n];
        if (b1) bs += b1[n];
#pragma unroll
        for (int mt = 0; mt < 4; ++mt) {
#pragma unroll
            for (int reg = 0; reg < 4; ++reg) {
                int gr = r0 + mt * 16 + rquad + reg;
                if (gr < n_rows) {
                    float v = acc[mt][c][reg] + bs;
                    if (relu) v = v > 0.f ? v : 0.01f * v;
                    size_t o = (size_t)gr * H + n;
                    out16[o] = (_Float16)v;
                    short h = f2bf(v);
                    ohi[o] = h;
                    olo[o] = f2bf(v - bf2f(h));
                }
            }
        }
    }
}

// ---------------- edge decoder: sigmoid(dot(xp[i], xg[j])) on fp16 mirrors ----------------

__global__ __launch_bounds__(256) void scores_kernel(const _Float16* __restrict__ xp,
                                                     const _Float16* __restrict__ xg,
                                                     const int* __restrict__ eli, int E,
                                                     float* __restrict__ out) {
    int lane16 = threadIdx.x & 15;
    int sub = threadIdx.x >> 4;     // 16 edges per block
    int e = blockIdx.x * 16 + sub;
    if (e >= E) return;
    int ip = eli[e];
    int ig = eli[E + e];
    half8v a = *(const half8v*)&xp[(size_t)ip * H + lane16 * 8];
    half8v b = *(const half8v*)&xg[(size_t)ig * H + lane16 * 8];
    float s = 0.f;
#pragma unroll
    for (int k = 0; k < 8; ++k) s += (float)a[k] * (float)b[k];
#pragma unroll
    for (int off = 8; off; off >>= 1) s += __shfl_xor(s, off, 16);
    if (lane16 == 0) out[e] = 1.0f / (1.0f + expf(-s));
}

// ---------------- host ----------------

extern "C" void kernel_launch(void* const* d_in, const int* in_sizes, int n_in,
                              void* d_out, int out_size, void* d_ws, size_t ws_size,
                              hipStream_t stream) {
    const float* x_pheno = (const float*)d_in[0];
    const float* x_gene  = (const float*)d_in[1];
    const float* Wl_isa  = (const float*)d_in[2];
    const float* bl_isa  = (const float*)d_in[3];
    const float* Wr_isa  = (const float*)d_in[4];
    const float* Wl_rel  = (const float*)d_in[5];
    const float* bl_rel  = (const float*)d_in[6];
    const float* Wr_rel  = (const float*)d_in[7];
    const float* Wl_rev  = (const float*)d_in[8];
    const float* bl_rev  = (const float*)d_in[9];
    const float* Wr_rev  = (const float*)d_in[10];
    const int* e_isa = (const int*)d_in[11];
    const int* e_rel = (const int*)d_in[12];
    const int* e_rev = (const int*)d_in[13];
    const int* e_lbl = (const int*)d_in[14];
    const int E_isa = in_sizes[11] / 2;
    const int E_rel = in_sizes[12] / 2;
    const int E_rev = in_sizes[13] / 2;
    const int E_lbl = in_sizes[14] / 2;
    const int NP = in_sizes[0] / H;
    const int NG = in_sizes[1] / H;
    const int n_tot = NP + NG + NP;
    const int E_tot = E_isa + E_rel + E_rev;
    const int nbins = (n_tot + BINW - 1) / BINW;

    char* ws = (char*)d_ws;
    auto alloc = [&](size_t bytes) -> char* {
        char* p = ws;
        ws += (bytes + 255) & ~(size_t)255;
        return p;
    };
    int* rowptr  = (int*)alloc((size_t)(n_tot + 1) * 4);
    int* col     = (int*)alloc((size_t)E_tot * 4);
    int* temp    = (int*)alloc((size_t)nbins * BSLOT * 4);
    int* bin_cur = (int*)alloc((size_t)nbins * 16 * 4);   // 64B-strided counters
    int* bin_base= (int*)alloc((size_t)(nbins + 1) * 4);
    short* whi = (short*)alloc((size_t)15 * H * H * sizeof(short));
    short* wlo = (short*)alloc((size_t)15 * H * H * sizeof(short));
    _Float16* xpm[2], *xgm[2];
    xpm[0] = (_Float16*)alloc((size_t)NP * H * sizeof(_Float16));
    xpm[1] = (_Float16*)alloc((size_t)NP * H * sizeof(_Float16));
    xgm[0] = (_Float16*)alloc((size_t)NG * H * sizeof(_Float16));
    xgm[1] = (_Float16*)alloc((size_t)NG * H * sizeof(_Float16));
    short* xph = (short*)alloc((size_t)NP * H * sizeof(short));
    short* xpl = (short*)alloc((size_t)NP * H * sizeof(short));
    short* xgh = (short*)alloc((size_t)NG * H * sizeof(short));
    short* xgl = (short*)alloc((size_t)NG * H * sizeof(short));

    // ---- CSR build (every call; ws is re-poisoned by the harness) ----
    hipMemsetAsync(bin_cur, 0, (size_t)nbins * 16 * 4, stream);
    bin_scatter_kernel<<<(E_tot + KEDGE - 1) / KEDGE, 256, 0, stream>>>(
        e_isa, E_isa, e_rel, E_rel, e_rev, E_rev, bin_cur, temp, NP, NG, nbins, E_tot);
    scan_bins<<<1, 1024, 0, stream>>>(bin_cur, nbins, bin_base);
    bin_sort_kernel<<<nbins, 256, 0, stream>>>(bin_base, temp, col, rowptr, n_tot, nbins);

    // ---- W pack: per layer slots {Wl_isa, Wl_rev, Wsum=Wr_isa+Wr_rev, Wl_rel, Wr_rel} ----
    WSrc src;
    for (int l = 0; l < 3; ++l) {
        src.a[l * 5 + 0] = Wl_isa + (size_t)l * H * H;  src.b[l * 5 + 0] = nullptr;
        src.a[l * 5 + 1] = Wl_rev + (size_t)l * H * H;  src.b[l * 5 + 1] = nullptr;
        src.a[l * 5 + 2] = Wr_isa + (size_t)l * H * H;  src.b[l * 5 + 2] = Wr_rev + (size_t)l * H * H;
        src.a[l * 5 + 3] = Wl_rel + (size_t)l * H * H;  src.b[l * 5 + 3] = nullptr;
        src.a[l * 5 + 4] = Wr_rel + (size_t)l * H * H;  src.b[l * 5 + 4] = nullptr;
    }
    pack_w_kernel<<<(15 * 4 * 8 * 64 + 255) / 256, 256, 0, stream>>>(src, whi, wlo);

    // ---- layer-0 fp16 mirrors of the inputs (set 0) ----
    cvt16_kernel<<<((NP + NG) * 32 + 255) / 256, 256, 0, stream>>>(
        x_pheno, NP * 32, x_gene, NG * 32, xpm[0], xgm[0]);

    // ---- 3 fused layers ----
    // Mirrors ping-pong (read set rs = l&1, write set rs^1) so NG-fused can read old
    // xp16 after NP-fused ran. Planes are single-buffered: each kernel reads its own
    // rows before the epilogue overwrites them (block-local, proven pattern).
    const short *pph = nullptr, *ppl = nullptr, *pgh = nullptr, *pgl = nullptr;
    for (int l = 0; l < 3; ++l) {
        int rs = l & 1;
        int wsid = rs ^ 1;
        int relu = (l < 2) ? 1 : 0;
        const float* bli = bl_isa + (size_t)l * H;
        const float* blv = bl_rev + (size_t)l * H;
        const float* blr = bl_rel + (size_t)l * H;
        // new_p = isa-mean(xp)@Wl_isa + rev-mean(xg)@Wl_rev + xp@(Wr_isa+Wr_rev) + biases
        GTerm isa{xpm[rs], 0, nullptr, nullptr, nullptr};
        GTerm rev{xgm[rs], NP + NG, nullptr, nullptr, nullptr};
        GTerm xpt{nullptr, 0, pph, ppl, l == 0 ? x_pheno : nullptr};
        fused_gnn<3><<<(NP + 63) / 64, 256, 0, stream>>>(
            isa, rev, xpt, rowptr, col, whi, wlo, l * 5 + 0, l * 5 + 1, l * 5 + 2,
            bli, blv, xpm[wsid], xph, xpl, NP, relu);
        // new_g = rel-mean(xp)@Wl_rel + xg@Wr_rel + bl_rel
        GTerm rel{xpm[rs], NP, nullptr, nullptr, nullptr};
        GTerm xgt{nullptr, 0, pgh, pgl, l == 0 ? x_gene : nullptr};
        GTerm nil{nullptr, 0, nullptr, nullptr, nullptr};
        fused_gnn<2><<<(NG + 63) / 64, 256, 0, stream>>>(
            rel, xgt, nil, rowptr, col, whi, wlo, l * 5 + 3, l * 5 + 4, 0,
            blr, nullptr, xgm[wsid], xgh, xgl, NG, relu);
        pph = xph; ppl = xpl; pgh = xgh; pgl = xgl;
    }

    // ---- decoder (layer 2 wrote mirror set 1) ----
    scores_kernel<<<(E_lbl + 15) / 16, 256, 0, stream>>>(xpm[1], xgm[1], e_lbl, E_lbl,
                                                         (float*)d_out);
}